// Round 1
// baseline (99.999 us; speedup 1.0000x reference)
//
#include <hip/hip_runtime.h>

#define NC 21
#define NB (NC * NC)      // 441 joint bins
#define NWAVES 8          // 512-thread blocks
#define HPAD 448          // per-wave histogram stride (multiple of 32 banks)

__global__ void __launch_bounds__(512) zero_hist(unsigned* __restrict__ h) {
    int i = threadIdx.x;
    if (i < NB) h[i] = 0;
}

__global__ void __launch_bounds__(512) hist_kernel(const int* __restrict__ pred,
                                                   const int* __restrict__ gt,
                                                   unsigned* __restrict__ g_hist,
                                                   int n) {
    __shared__ unsigned h[NWAVES][HPAD];
    const int tid = threadIdx.x;
    const int wave = tid >> 6;

    // zero LDS histograms
    for (int i = tid; i < NWAVES * HPAD; i += blockDim.x) (&h[0][0])[i] = 0;
    __syncthreads();

    const int n4 = n >> 2;
    const int4* __restrict__ p4 = (const int4*)pred;
    const int4* __restrict__ g4 = (const int4*)gt;
    const int stride = gridDim.x * blockDim.x;
    int gidx = blockIdx.x * blockDim.x + tid;

    for (int i = gidx; i < n4; i += stride) {
        int4 p = p4[i];
        int4 g = g4[i];
        atomicAdd(&h[wave][p.x + NC * g.x], 1u);
        atomicAdd(&h[wave][p.y + NC * g.y], 1u);
        atomicAdd(&h[wave][p.z + NC * g.z], 1u);
        atomicAdd(&h[wave][p.w + NC * g.w], 1u);
    }
    // scalar tail (n % 4 != 0) — no-op for this problem size
    for (int i = (n4 << 2) + gidx; i < n; i += stride) {
        atomicAdd(&h[wave][pred[i] + NC * gt[i]], 1u);
    }
    __syncthreads();

    // reduce per-wave hists, one global atomic per bin per block
    for (int i = tid; i < NB; i += blockDim.x) {
        unsigned s = 0;
        #pragma unroll
        for (int w = 0; w < NWAVES; ++w) s += h[w][i];
        if (s) atomicAdd(&g_hist[i], s);
    }
}

__global__ void __launch_bounds__(64) miou_final(const unsigned* __restrict__ h,
                                                 float* __restrict__ out) {
    const int lane = threadIdx.x;
    float iou = 0.0f;
    if (lane < NC) {
        float pc = 0.0f, gc = 0.0f;
        #pragma unroll
        for (int g = 0; g < NC; ++g) pc += (float)h[lane + NC * g];   // pred_counts[lane]
        #pragma unroll
        for (int p = 0; p < NC; ++p) gc += (float)h[p + NC * lane];   // gt_counts[lane]
        float inter = (float)h[lane * (NC + 1)];                       // diagonal
        float uni = pc + gc - inter;
        iou = (inter + 1e-7f) / (uni + 1e-7f);
    }
    // wave64 shuffle reduce (lanes >= 21 contribute 0)
    for (int off = 32; off; off >>= 1) iou += __shfl_down(iou, off);
    if (lane == 0) out[0] = iou * (1.0f / 21.0f);
}

extern "C" void kernel_launch(void* const* d_in, const int* in_sizes, int n_in,
                              void* d_out, int out_size, void* d_ws, size_t ws_size,
                              hipStream_t stream) {
    const int* pred = (const int*)d_in[0];
    const int* gt   = (const int*)d_in[1];
    unsigned* g_hist = (unsigned*)d_ws;
    float* out = (float*)d_out;
    const int n = in_sizes[0];

    zero_hist<<<1, 512, 0, stream>>>(g_hist);
    hist_kernel<<<512, 512, 0, stream>>>(pred, gt, g_hist, n);
    miou_final<<<1, 64, 0, stream>>>(g_hist, out);
}